// Round 2
// 240.866 us; speedup vs baseline: 1.0011x; 1.0011x over previous
//
#include <hip/hip_runtime.h>

#define B_    16
#define T_    8
#define K_    64
#define COUT  128
#define CIN   128
#define H_    64
#define W_    64
#define WSZ   (COUT*CIN*5*5)        // 409600 per-k (and per-b) weight elems

typedef __bf16 bf16x8 __attribute__((ext_vector_type(8)));
typedef float  f32x4  __attribute__((ext_vector_type(4)));

static __device__ __forceinline__ unsigned short f2bf(float f) {
    unsigned int u = __builtin_bit_cast(unsigned int, f);
    unsigned int r = (u + 0x7FFFu + ((u >> 16) & 1u)) >> 16;
    return (unsigned short)r;
}

static __device__ __forceinline__ unsigned int pack2(float lo, float hi) {
    return (unsigned int)f2bf(lo) | ((unsigned int)f2bf(hi) << 16);
}

// ---------------------------------------------------------------------------
// Fused prep kernel. Grid 1536 blocks:
//   blocks [0,512):    lp role  — weight-gen + MFMA-A fragment repack
//   blocks [512,1536): xtrans role — x fp32 NCHW -> xT bf16 [b][h][w][c]
// lp role: 8-deep explicit prefetch ring on the k-strided Wb stream so 8
// loads (128 B/lane) stay in flight across the FMA block (latency fix).
// xtrans role: register-only transpose — float4 loads along w, bf16 pack in
// regs, dwordx4 stores. No LDS, no barrier.
// ---------------------------------------------------------------------------
__global__ __launch_bounds__(256) void prep_kernel(const float* __restrict__ Wb,
                                                   const float* __restrict__ tf,
                                                   const float* __restrict__ x,
                                                   unsigned short* __restrict__ lpF,
                                                   unsigned short* __restrict__ xT) {
    __shared__ __align__(16) char smem[30720];
    int tid = threadIdx.x;

    if (blockIdx.x < 512) {
        // ---------------- lp role ----------------
        // lpF[b][tap][kc(4)][wm(2)][mt(4)][lane(64)][j(8)]  (bf16)
        //   o = wm*64 + mt*16 + (lane&15), c = kc*32 + (lane>>4)*8 + j
        float* cs2         = (float*)smem;                       // [64][16] = 4 KB
        unsigned short* lt = (unsigned short*)(smem + 4096);     // 25.6 KB

        int o = blockIdx.x >> 2;      // 0..127
        int s = blockIdx.x & 3;       // c chunk: c in [32s, 32s+32)

        // coef transposed: cs2[k*16 + b] = mean_t tf[b,t,k] * 0.125
        {
            int idx = tid;
#pragma unroll
            for (int r = 0; r < 4; ++r, idx += 256) {
                int k = idx >> 4, b = idx & 15;
                float sum = 0.f;
#pragma unroll
                for (int t = 0; t < T_; ++t) sum += tf[(b * T_ + t) * K_ + k];
                cs2[idx] = sum * 0.125f;
            }
        }
        __syncthreads();

        if (tid < 200) {
            const float* wp = Wb + o * 3200 + s * 800 + tid * 4;
            float4 acc[B_];
#pragma unroll
            for (int b = 0; b < B_; ++b) acc[b] = make_float4(0.f, 0.f, 0.f, 0.f);

#define LP_FMA(K_IDX, WV) do {                                               \
    const float4* cp_ = (const float4*)(cs2 + ((K_IDX) << 4));               \
    float4 c0_ = cp_[0], c1_ = cp_[1], c2_ = cp_[2], c3_ = cp_[3];           \
    acc[0].x  += c0_.x * (WV).x; acc[0].y  += c0_.x * (WV).y;                \
    acc[0].z  += c0_.x * (WV).z; acc[0].w  += c0_.x * (WV).w;                \
    acc[1].x  += c0_.y * (WV).x; acc[1].y  += c0_.y * (WV).y;                \
    acc[1].z  += c0_.y * (WV).z; acc[1].w  += c0_.y * (WV).w;                \
    acc[2].x  += c0_.z * (WV).x; acc[2].y  += c0_.z * (WV).y;                \
    acc[2].z  += c0_.z * (WV).z; acc[2].w  += c0_.z * (WV).w;                \
    acc[3].x  += c0_.w * (WV).x; acc[3].y  += c0_.w * (WV).y;                \
    acc[3].z  += c0_.w * (WV).z; acc[3].w  += c0_.w * (WV).w;                \
    acc[4].x  += c1_.x * (WV).x; acc[4].y  += c1_.x * (WV).y;                \
    acc[4].z  += c1_.x * (WV).z; acc[4].w  += c1_.x * (WV).w;                \
    acc[5].x  += c1_.y * (WV).x; acc[5].y  += c1_.y * (WV).y;                \
    acc[5].z  += c1_.y * (WV).z; acc[5].w  += c1_.y * (WV).w;                \
    acc[6].x  += c1_.z * (WV).x; acc[6].y  += c1_.z * (WV).y;                \
    acc[6].z  += c1_.z * (WV).z; acc[6].w  += c1_.z * (WV).w;                \
    acc[7].x  += c1_.w * (WV).x; acc[7].y  += c1_.w * (WV).y;                \
    acc[7].z  += c1_.w * (WV).z; acc[7].w  += c1_.w * (WV).w;                \
    acc[8].x  += c2_.x * (WV).x; acc[8].y  += c2_.x * (WV).y;                \
    acc[8].z  += c2_.x * (WV).z; acc[8].w  += c2_.x * (WV).w;                \
    acc[9].x  += c2_.y * (WV).x; acc[9].y  += c2_.y * (WV).y;                \
    acc[9].z  += c2_.y * (WV).z; acc[9].w  += c2_.y * (WV).w;                \
    acc[10].x += c2_.z * (WV).x; acc[10].y += c2_.z * (WV).y;                \
    acc[10].z += c2_.z * (WV).z; acc[10].w += c2_.z * (WV).w;                \
    acc[11].x += c2_.w * (WV).x; acc[11].y += c2_.w * (WV).y;                \
    acc[11].z += c2_.w * (WV).z; acc[11].w += c2_.w * (WV).w;                \
    acc[12].x += c3_.x * (WV).x; acc[12].y += c3_.x * (WV).y;                \
    acc[12].z += c3_.x * (WV).z; acc[12].w += c3_.x * (WV).w;                \
    acc[13].x += c3_.y * (WV).x; acc[13].y += c3_.y * (WV).y;                \
    acc[13].z += c3_.y * (WV).z; acc[13].w += c3_.y * (WV).w;                \
    acc[14].x += c3_.z * (WV).x; acc[14].y += c3_.z * (WV).y;                \
    acc[14].z += c3_.z * (WV).z; acc[14].w += c3_.z * (WV).w;                \
    acc[15].x += c3_.w * (WV).x; acc[15].y += c3_.w * (WV).y;                \
    acc[15].z += c3_.w * (WV).z; acc[15].w += c3_.w * (WV).w;                \
} while (0)

            // 8-deep prefetch ring: 8 strided Wb loads always in flight.
            float4 wbuf[8];
#pragma unroll
            for (int u = 0; u < 8; ++u)
                wbuf[u] = *(const float4*)(wp + (size_t)u * WSZ);

            for (int kb = 0; kb < 56; kb += 8) {
#pragma unroll
                for (int u = 0; u < 8; ++u) {
                    float4 wv = wbuf[u];
                    wbuf[u] = *(const float4*)(wp + (size_t)(kb + u + 8) * WSZ);
                    LP_FMA(kb + u, wv);
                }
            }
#pragma unroll
            for (int u = 0; u < 8; ++u) {
                float4 wv = wbuf[u];
                LP_FMA(56 + u, wv);
            }
#undef LP_FMA

            unsigned int* ltw = (unsigned int*)lt;
#pragma unroll
            for (int b = 0; b < B_; ++b) {
                ltw[b * 400 + tid * 2]     = pack2(acc[b].x, acc[b].y);
                ltw[b * 400 + tid * 2 + 1] = pack2(acc[b].z, acc[b].w);
            }
        }
        __syncthreads();

        // fragment-ordered writeout: wm,mt,n16 fixed per block; quad varies
        int wm = o >> 6, mt = (o >> 4) & 3, n16 = o & 15;
        for (int it = tid; it < 1600; it += 256) {
            int b = it / 100;
            int r = it - b * 100;
            int tap = r >> 2;
            int quad = r & 3;
            unsigned short v[8];
#pragma unroll
            for (int j = 0; j < 8; ++j)
                v[j] = lt[b * 800 + (quad * 8 + j) * 25 + tap];
            size_t off = (size_t)b * 409600
                       + (size_t)((((tap * 4 + s) * 2 + wm) * 4 + mt) * 512
                                  + quad * 128 + n16 * 8);
            *(uint4*)(lpF + off) = *(const uint4*)v;
        }
    } else {
        // ---------------- xtrans role (register-only) ----------------
        // thread: w4 = tid&15 (4 consecutive w), c16 = tid>>4 (8 consecutive c)
        int q = blockIdx.x - 512;
        int b = q >> 6, h = q & 63;
        int w4 = tid & 15, c16 = tid >> 4;

        const float* xp = x + (((size_t)(b * CIN + c16 * 8) * H_ + h) * W_) + w4 * 4;

        unsigned int r0[4], r1[4], r2[4], r3[4];
#pragma unroll
        for (int p = 0; p < 4; ++p) {
            float4 a = *(const float4*)(xp + (size_t)(2 * p)     * (H_ * W_));
            float4 c = *(const float4*)(xp + (size_t)(2 * p + 1) * (H_ * W_));
            r0[p] = pack2(a.x, c.x);
            r1[p] = pack2(a.y, c.y);
            r2[p] = pack2(a.z, c.z);
            r3[p] = pack2(a.w, c.w);
        }

        unsigned short* xTb = xT + (((size_t)(b * 64 + h) * 64 + w4 * 4) * 128) + c16 * 8;
        uint4 q0; q0.x = r0[0]; q0.y = r0[1]; q0.z = r0[2]; q0.w = r0[3];
        uint4 q1; q1.x = r1[0]; q1.y = r1[1]; q1.z = r1[2]; q1.w = r1[3];
        uint4 q2; q2.x = r2[0]; q2.y = r2[1]; q2.z = r2[2]; q2.w = r2[3];
        uint4 q3; q3.x = r3[0]; q3.y = r3[1]; q3.z = r3[2]; q3.w = r3[3];
        *(uint4*)(xTb)           = q0;
        *(uint4*)(xTb + 128)     = q1;
        *(uint4*)(xTb + 256)     = q2;
        *(uint4*)(xTb + 384)     = q3;
    }
}

// ---------------------------------------------------------------------------
// Conv as 25 shifted GEMMs, bf16 MFMA 16x16x32, fp32 accum.
// Round-3 proven structure (2-deep pipeline, VGPR 72).
// Grid: 512 blocks, XCD-swizzled (2 batches per XCD's L2).
// Block tile: M=128 (o) x N=128 (2 rows x 64 w). Wave: 64x64 (4mt x 4nt).
// ---------------------------------------------------------------------------
__global__ __launch_bounds__(256) void conv_mfma(const unsigned short* __restrict__ xT,
                                                 const unsigned short* __restrict__ lpF,
                                                 float* __restrict__ out) {
    int bid = blockIdx.x;
    int b  = (bid & 7) | (((bid >> 3) & 1) << 3);   // XCD-local batch
    int h0 = (bid >> 4) << 1;                       // row pair

    int tid  = threadIdx.x;
    int lane = tid & 63, wid = tid >> 6;
    int wm = wid & 1, wn = wid >> 1;          // wm: o-half, wn: output row
    int n16 = lane & 15, quad = lane >> 4;

    __shared__ __align__(16) unsigned short xs[408 * 40];   // 32640 B

    f32x4 acc[4][4];
#pragma unroll
    for (int mt = 0; mt < 4; ++mt)
#pragma unroll
        for (int nt = 0; nt < 4; ++nt) acc[mt][nt] = (f32x4){0.f, 0.f, 0.f, 0.f};

    const unsigned short* xTb = xT + (size_t)b * (64 * 64 * 128);
    const unsigned short* lpW = lpF + (size_t)b * 409600 + wm * 2048 + lane * 8;

#define LOAD_FRAGS(A, Bf, tap) do {                                          \
    int i_ = (tap) / 5, j_ = (tap) - 5 * (i_);                               \
    const unsigned short* ap_ = lpW + (tap) * 16384 + kcB;                   \
    A[0] = *(const bf16x8*)(ap_);                                            \
    A[1] = *(const bf16x8*)(ap_ + 512);                                      \
    A[2] = *(const bf16x8*)(ap_ + 1024);                                     \
    A[3] = *(const bf16x8*)(ap_ + 1536);                                     \
    const unsigned short* bp_ = &xs[(((wn + i_) * 68) + n16 + j_) * 40 + quad * 8]; \
    Bf[0] = *(const bf16x8*)(bp_);                                           \
    Bf[1] = *(const bf16x8*)(bp_ + 16 * 40);                                 \
    Bf[2] = *(const bf16x8*)(bp_ + 32 * 40);                                 \
    Bf[3] = *(const bf16x8*)(bp_ + 48 * 40);                                 \
} while (0)

#define DO_MFMA(av, bv) do {                                                 \
    _Pragma("unroll") for (int mt = 0; mt < 4; ++mt)                         \
    _Pragma("unroll") for (int nt = 0; nt < 4; ++nt)                         \
        acc[mt][nt] = __builtin_amdgcn_mfma_f32_16x16x32_bf16(               \
            (av)[mt], (bv)[nt], acc[mt][nt], 0, 0, 0);                       \
} while (0)

    for (int kc = 0; kc < 4; ++kc) {
        int kcOff = kc * 32;
        int kcB   = kc * 4096;
        __syncthreads();                       // previous chunk's readers done
        // stage x rows h0-2 .. h0+3, cols -2..65 (zeros outside), 32 channels
        for (int sIdx = tid; sIdx < 408; sIdx += 256) {
            unsigned int su = (unsigned int)sIdx;
            int rr = su / 68u;
            int ww = su - rr * 68u;
            int gr = h0 - 2 + rr, gw = ww - 2;
            uint4* dst = (uint4*)&xs[sIdx * 40];
            if ((unsigned)gr < 64u && (unsigned)gw < 64u) {
                const uint4* src = (const uint4*)(xTb + (((size_t)gr * 64 + gw) * 128 + kcOff));
                dst[0] = src[0]; dst[1] = src[1]; dst[2] = src[2]; dst[3] = src[3];
            } else {
                uint4 z = {0u, 0u, 0u, 0u};
                dst[0] = z; dst[1] = z; dst[2] = z; dst[3] = z;
            }
        }
        __syncthreads();

        bf16x8 a0[4], b0[4], a1[4], b1[4];
        LOAD_FRAGS(a0, b0, 0);
        for (int t = 0; t < 24; t += 2) {
            LOAD_FRAGS(a1, b1, t + 1);
            DO_MFMA(a0, b0);
            LOAD_FRAGS(a0, b0, t + 2);
            DO_MFMA(a1, b1);
        }
        DO_MFMA(a0, b0);                       // tap 24
    }

    // epilogue: D row (o) = quad*4 + reg, D col (pixel) = lane&15
    float* outb = out + (size_t)b * (COUT * H_ * W_) + (size_t)(h0 + wn) * W_;
#pragma unroll
    for (int mt = 0; mt < 4; ++mt) {
#pragma unroll
        for (int nt = 0; nt < 4; ++nt) {
#pragma unroll
            for (int r = 0; r < 4; ++r) {
                int o = wm * 64 + mt * 16 + quad * 4 + r;
                int w = nt * 16 + n16;
                outb[(size_t)o * (H_ * W_) + w] = acc[mt][nt][r];
            }
        }
    }
#undef LOAD_FRAGS
#undef DO_MFMA
}

// ---------------------------------------------------------------------------
extern "C" void kernel_launch(void* const* d_in, const int* in_sizes, int n_in,
                              void* d_out, int out_size, void* d_ws, size_t ws_size,
                              hipStream_t stream) {
    const float* x  = (const float*)d_in[0];   // (16,128,64,64)
    const float* tf = (const float*)d_in[1];   // (16,8,64)
    const float* Wb = (const float*)d_in[2];   // (64,128,128,5,5)
    float* out = (float*)d_out;                // (16,128,64,64) fp32

    // ws: lpF bf16 fragment-ordered 16*409600 = 13.1 MB, then xT bf16 16.8 MB
    unsigned short* lpF = (unsigned short*)d_ws;
    unsigned short* xT  = lpF + (size_t)B_ * 409600;

    prep_kernel<<<1536, 256, 0, stream>>>(Wb, tf, x, lpF, xT);
    conv_mfma  <<<512,  256, 0, stream>>>(xT, lpF, out);
}